// Round 1
// baseline (44921.921 us; speedup 1.0000x reference)
//
#include <hip/hip_runtime.h>
#include <cmath>

#define NHID 512
#define NXW  128
#define TLEN 16384
#define STEPS (TLEN - NXW)      // 16256
#define G    16                 // persistent workgroups
#define B    512                // threads per WG (8 waves)
#define RPW  (NHID / G)         // 32 hidden rows owned per WG

// ---------------------------------------------------------------------------
// init: zero the per-WG arrival flags (ws is re-poisoned 0xAA before every call)
// ---------------------------------------------------------------------------
__global__ void init_flags(int* flags) {
    if (threadIdx.x < G) flags[threadIdx.x] = 0;
}

// ---------------------------------------------------------------------------
// persistent LSTM recurrence. WG g owns hidden rows [g*32, g*32+32).
// thread layout: out = tid & 127 (q = out>>5 gate, j = out&31 row),
//                s   = tid >> 7  (k-slice of 128; wave-uniform -> LDS broadcast)
// ---------------------------------------------------------------------------
__launch_bounds__(B, 2)
__global__ void lstm_persistent(
    const float* __restrict__ x,
    const float* __restrict__ Wf, const float* __restrict__ Uf, const float* __restrict__ bf,
    const float* __restrict__ Wi, const float* __restrict__ Ui, const float* __restrict__ bi,
    const float* __restrict__ Wo, const float* __restrict__ Uo, const float* __restrict__ bo,
    const float* __restrict__ Wc, const float* __restrict__ Uc, const float* __restrict__ bc,
    float* __restrict__ h_hist,   // [STEPS][NHID] in ws
    int*   __restrict__ flags)    // [G] in ws
{
    __shared__ float x_win[256];                    // ring buffer: refill every 128 steps
    __shared__ __align__(16) float h_lds[NHID];
    __shared__ float partials[B];
    __shared__ float act[128];
    __shared__ float bias_lds[128];
    __shared__ float c_lds[RPW];

    const int tid = threadIdx.x;
    const int g   = blockIdx.x;
    const int out = tid & 127;
    const int q   = out >> 5;       // 0=f 1=i 2=o 3=c
    const int j   = out & 31;
    const int s   = tid >> 7;       // 0..3, wave-uniform
    const int row = g * RPW + j;

    const float* Utab[4] = {Uf, Ui, Uo, Uc};
    const float* Wtab[4] = {Wf, Wi, Wo, Wc};
    const float* Btab[4] = {bf, bi, bo, bc};

    if (tid < NHID) h_lds[tid] = 0.f;
    if (tid < RPW)  c_lds[tid] = 0.f;
    if (tid < 128)  bias_lds[tid] = Btab[q][row];

    // pin weights in VGPRs: 128 U-floats + 32 W-floats per thread
    float4 u[32];
    {
        const float4* Up = (const float4*)(Utab[q] + (size_t)row * NHID + s * 128);
        #pragma unroll
        for (int kk = 0; kk < 32; kk++) u[kk] = Up[kk];
    }
    float wv[32];
    {
        const float* Wp = Wtab[q] + row * NXW + s * 32;
        #pragma unroll
        for (int mm = 0; mm < 32; mm++) wv[mm] = Wp[mm];
    }
    __syncthreads();

    bool alive = true;
    for (int t = 0; t < STEPS; t++) {
        // refill x ring buffer every 128 steps
        if ((t & 127) == 0) {
            if (tid < 256) {
                int gi = t + tid;
                x_win[tid] = (gi < TLEN) ? x[gi] : 0.f;
            }
            __syncthreads();
        }

        // A: x-projection slice (independent of h -> overlaps the wait)
        float xacc = 0.f;
        {
            const int xb = (t & 127) + s * 32;
            #pragma unroll
            for (int mm = 0; mm < 32; mm++) xacc += wv[mm] * x_win[xb + mm];
        }

        // B: wait for all WGs to have published h[t-1], then broadcast to LDS
        if (t > 0) {
            if (tid < 64 && alive) {        // wave 0 polls
                int guard = 0; bool ok;
                do {
                    int v = (tid < G)
                        ? __hip_atomic_load(&flags[tid], __ATOMIC_RELAXED, __HIP_MEMORY_SCOPE_AGENT)
                        : 0x7fffffff;
                    ok = __all(v >= t);
                } while (!ok && ++guard < (1 << 21));
                if (!ok) alive = false;     // bail instead of hanging the harness
            }
            __syncthreads();                // #1
            h_lds[tid] = __hip_atomic_load(&h_hist[(size_t)(t - 1) * NHID + tid],
                                           __ATOMIC_RELAXED, __HIP_MEMORY_SCOPE_AGENT);
            __syncthreads();                // #2
        }

        // C: U @ h partial (128 FMA/thread, h via wave-uniform LDS broadcast)
        float acc = 0.f;
        {
            const float4* h4 = (const float4*)h_lds;
            #pragma unroll
            for (int kk = 0; kk < 32; kk++) {
                float4 hv = h4[s * 32 + kk];
                float4 uu = u[kk];
                acc += uu.x * hv.x + uu.y * hv.y + uu.z * hv.z + uu.w * hv.w;
            }
        }
        partials[tid] = acc + xacc;
        __syncthreads();                    // #3

        // D: reduce 4 k-slices + bias + activation
        if (tid < 128) {
            float pre = partials[tid] + partials[tid + 128] + partials[tid + 256]
                      + partials[tid + 384] + bias_lds[tid];
            float a = (tid < 96) ? (1.f / (1.f + __expf(-pre))) : tanhf(pre);
            act[tid] = a;
        }
        __syncthreads();                    // #4

        // E: gate combine, private c update, publish h slice + flag (wave 0)
        if (tid < RPW) {
            float f  = act[tid];
            float ii = act[32 + tid];
            float o  = act[64 + tid];
            float gg = act[96 + tid];
            float c  = f * c_lds[tid] + ii * gg;
            c_lds[tid] = c;
            float h = o * tanhf(c);
            __hip_atomic_store(&h_hist[(size_t)t * NHID + g * RPW + tid], h,
                               __ATOMIC_RELAXED, __HIP_MEMORY_SCOPE_AGENT);
        }
        if (tid == 0) {
            // release drains wave 0's h stores (same wave) before the flag lands
            __hip_atomic_store(&flags[g], t + 1, __ATOMIC_RELEASE, __HIP_MEMORY_SCOPE_AGENT);
        }
        // no trailing barrier: wave 0 does E + next poll; others park at #1
    }
}

// ---------------------------------------------------------------------------
// epilogue: mu[t] = Ahy . h_hist[t] + by   (one wave per t)
// ---------------------------------------------------------------------------
__global__ void mu_kernel(const float* __restrict__ h_hist,
                          const float* __restrict__ Ahy,
                          const float* __restrict__ by,
                          float* __restrict__ outp, int steps)
{
    int wave = threadIdx.x >> 6;
    int lane = threadIdx.x & 63;
    int t = blockIdx.x * 4 + wave;
    if (t >= steps) return;
    const float* h = h_hist + (size_t)t * NHID;
    float p = 0.f;
    #pragma unroll
    for (int e = 0; e < 8; e++) p += Ahy[e * 64 + lane] * h[e * 64 + lane];
    #pragma unroll
    for (int off = 32; off; off >>= 1) p += __shfl_down(p, off, 64);
    if (lane == 0) outp[t] = p + by[0];
}

// ---------------------------------------------------------------------------
extern "C" void kernel_launch(void* const* d_in, const int* in_sizes, int n_in,
                              void* d_out, int out_size, void* d_ws, size_t ws_size,
                              hipStream_t stream)
{
    const float* x  = (const float*)d_in[0];
    const float* Wf = (const float*)d_in[1];
    const float* Uf = (const float*)d_in[2];
    const float* bf = (const float*)d_in[3];
    const float* Wi = (const float*)d_in[4];
    const float* Ui = (const float*)d_in[5];
    const float* bi = (const float*)d_in[6];
    const float* Wo = (const float*)d_in[7];
    const float* Uo = (const float*)d_in[8];
    const float* bo = (const float*)d_in[9];
    const float* Wc = (const float*)d_in[10];
    const float* Uc = (const float*)d_in[11];
    const float* bc = (const float*)d_in[12];
    const float* Ahy = (const float*)d_in[13];
    const float* by  = (const float*)d_in[14];

    int*   flags  = (int*)d_ws;
    float* h_hist = (float*)((char*)d_ws + 1024);   // needs ~33.3 MB of ws

    init_flags<<<1, 64, 0, stream>>>(flags);
    lstm_persistent<<<G, B, 0, stream>>>(x, Wf, Uf, bf, Wi, Ui, bi,
                                         Wo, Uo, bo, Wc, Uc, bc, h_hist, flags);
    int muBlocks = (STEPS + 3) / 4;
    mu_kernel<<<muBlocks, 256, 0, stream>>>(h_hist, Ahy, by, (float*)d_out, STEPS);
}

// Round 2
// 33505.179 us; speedup vs baseline: 1.3407x; 1.3407x over previous
//
#include <hip/hip_runtime.h>

#define NHID 512
#define NXW  128
#define TLEN 16384
#define STEPS (TLEN - NXW)      // 16256
#define G    16                 // persistent workgroups (one CU each)
#define B    512                // threads per WG (8 waves)
#define RPW  32                 // hidden rows owned per WG

#define POISON_U 0xAAAAAAAAu    // harness re-poisons d_ws to 0xAA before every launch

#define FOR8(M)  M(0) M(1) M(2) M(3) M(4) M(5) M(6) M(7)
#define FOR32(M) M(0) M(1) M(2) M(3) M(4) M(5) M(6) M(7) \
                 M(8) M(9) M(10) M(11) M(12) M(13) M(14) M(15) \
                 M(16) M(17) M(18) M(19) M(20) M(21) M(22) M(23) \
                 M(24) M(25) M(26) M(27) M(28) M(29) M(30) M(31)

__device__ __forceinline__ float sigmoid_f(float v) { return 1.f / (1.f + __expf(-v)); }
// tanh via exp: saturates correctly at +/-inf of expf
__device__ __forceinline__ float tanh_f(float v) { return 1.f - 2.f / (1.f + __expf(2.f * v)); }

// ---------------------------------------------------------------------------
// Persistent LSTM recurrence, flag-less data polling.
//   wave w: k-slice s = w>>1 (128 h elems), output half (w&1)*64.
//   thread (w,l): out = ((w&1)<<6)|l, owns U[gate q][row][s*128..+128) in regs.
//   h published as h+2.0f (in (1,3)) -> never equals 0xAA poison; consumers
//   poll their own 8-byte word of h_hist[t-1] directly. One barrier per step.
// ---------------------------------------------------------------------------
__launch_bounds__(B, 2)
__global__ void lstm_persistent(
    const float* __restrict__ x,
    const float* __restrict__ Wf, const float* __restrict__ Uf, const float* __restrict__ bf,
    const float* __restrict__ Wi, const float* __restrict__ Ui, const float* __restrict__ bi,
    const float* __restrict__ Wo, const float* __restrict__ Uo, const float* __restrict__ bo,
    const float* __restrict__ Wc, const float* __restrict__ Uc, const float* __restrict__ bc,
    float* __restrict__ h_hist)   // [STEPS][NHID] in ws (poisoned 0xAA)
{
    __shared__ float x_win[256];                    // x ring: refilled every 128 steps
    __shared__ __align__(16) float h_buf[8][128];   // per-wave h chunk staging
    __shared__ float partials[2][B];                // double-buffered (no trailing barrier)

    const int tid = threadIdx.x;
    const int g   = blockIdx.x;
    const int w   = tid >> 6;            // wave 0..7
    const int l   = tid & 63;
    const int s   = w >> 1;              // k-slice 0..3
    const int out = ((w & 1) << 6) | l;  // 0..127
    const int q   = out >> 5;            // gate 0=f 1=i 2=o 3=c
    const int row = g * RPW + (out & 31);

    const float* Utab[4] = {Uf, Ui, Uo, Uc};
    const float* Wtab[4] = {Wf, Wi, Wo, Wc};
    const float* Btab[4] = {bf, bi, bo, bc};

    // --- pin weights in NAMED registers (prevents the R1 demotion to reloads) ---
    const float4* Up = (const float4*)(Utab[q] + (size_t)row * NHID + s * 128);
    #define DECLU(i) float4 u##i = Up[i];
    FOR32(DECLU)
    const float4* Wp = (const float4*)(Wtab[q] + row * NXW + s * 32);
    #define DECLW(i) float4 wv##i = Wp[i];
    FOR8(DECLW)

    // wave-0 tail state: bias pair + private cell state (lanes < 32)
    float bias0 = 0.f, bias1 = 0.f, c_prev = 0.f;
    if (w == 0) {
        bias0 = Btab[l >> 5][g * RPW + (l & 31)];        // f (l<32) / i (l>=32)
        bias1 = Btab[2 + (l >> 5)][g * RPW + (l & 31)];  // o (l<32) / g (l>=32)
    }

    // zero own h chunk for t=0 (only own wave reads h_buf[w])
    ((float2*)h_buf[w])[l] = make_float2(0.f, 0.f);

    for (int t = 0; t < STEPS; ++t) {
        // refill x window every 128 steps (covers x[t .. t+255])
        if ((t & 127) == 0) {
            __syncthreads();             // prior xacc reads done (via last partials barrier)
            if (tid < 256) {
                int gi = t + tid;
                x_win[tid] = (gi < TLEN) ? x[gi] : 0.f;
            }
            __syncthreads();
        }

        // x-projection partial (independent of h -> overlaps producer latency)
        float xacc = 0.f;
        {
            const int xb = (t & 127) + s * 32;
            #define XFMA(i) xacc += wv##i.x * x_win[xb + 4*i]     \
                                  + wv##i.y * x_win[xb + 4*i + 1] \
                                  + wv##i.z * x_win[xb + 4*i + 2] \
                                  + wv##i.w * x_win[xb + 4*i + 3];
            FOR8(XFMA)
        }

        // poll own 8 bytes of h[t-1] (flag-less: data != poison <=> published)
        if (t > 0) {
            const unsigned long long* src = (const unsigned long long*)
                (h_hist + (size_t)(t - 1) * NHID + s * 128 + l * 2);
            unsigned long long vv; unsigned lo, hi;
            int guard = 0;
            do {
                vv = __hip_atomic_load(src, __ATOMIC_RELAXED, __HIP_MEMORY_SCOPE_AGENT);
                lo = (unsigned)vv; hi = (unsigned)(vv >> 32);
                if (lo != POISON_U && hi != POISON_U) break;
            } while (++guard < (1 << 20));           // bounded: fail, don't hang
            float2 hv2;
            hv2.x = __uint_as_float(lo) - 2.0f;
            hv2.y = __uint_as_float(hi) - 2.0f;
            ((float2*)h_buf[w])[l] = hv2;            // own-wave staging, no barrier
        }

        // U @ h slice: 128 FMA vs wave-uniform LDS broadcast reads
        float acc = xacc;
        const float4* hb4 = (const float4*)h_buf[w];
        #define UFMA(i) { float4 hv = hb4[i];                         \
                          acc += u##i.x * hv.x + u##i.y * hv.y        \
                               + u##i.z * hv.z + u##i.w * hv.w; }
        FOR32(UFMA)
        partials[t & 1][tid] = acc;
        __syncthreads();                             // the ONE per-step barrier

        // wave-0 tail: reduce 4 slices, activate, combine via shuffle, publish
        if (w == 0) {
            const float* p = partials[t & 1];
            float pre0 = p[l]      + p[128 + l] + p[256 + l] + p[384 + l] + bias0;
            float pre1 = p[64 + l] + p[192 + l] + p[320 + l] + p[448 + l] + bias1;
            float a0 = sigmoid_f(pre0);                              // f / i
            float a1 = (l < 32) ? sigmoid_f(pre1) : tanh_f(pre1);    // o / g
            float ai = __shfl(a0, l + 32, 64);
            float ag = __shfl(a1, l + 32, 64);
            if (l < 32) {
                float c = a0 * c_prev + ai * ag;
                c_prev = c;
                float h = a1 * tanh_f(c);
                __hip_atomic_store(h_hist + (size_t)t * NHID + g * RPW + l,
                                   h + 2.0f,
                                   __ATOMIC_RELAXED, __HIP_MEMORY_SCOPE_AGENT);
            }
        }
        // waves 1..7 sprint ahead to poll step t's data (partials double-buffered)
    }
}

// ---------------------------------------------------------------------------
// epilogue: mu[t] = Ahy . (h_hist[t] - 2) + by   (one wave per t)
// ---------------------------------------------------------------------------
__global__ void mu_kernel(const float* __restrict__ h_hist,
                          const float* __restrict__ Ahy,
                          const float* __restrict__ by,
                          float* __restrict__ outp, int steps)
{
    int wave = threadIdx.x >> 6;
    int lane = threadIdx.x & 63;
    int t = blockIdx.x * 4 + wave;
    if (t >= steps) return;
    const float* h = h_hist + (size_t)t * NHID;
    float p = 0.f;
    #pragma unroll
    for (int e = 0; e < 8; e++)
        p += Ahy[e * 64 + lane] * (h[e * 64 + lane] - 2.0f);
    #pragma unroll
    for (int off = 32; off; off >>= 1) p += __shfl_down(p, off, 64);
    if (lane == 0) outp[t] = p + by[0];
}

// ---------------------------------------------------------------------------
extern "C" void kernel_launch(void* const* d_in, const int* in_sizes, int n_in,
                              void* d_out, int out_size, void* d_ws, size_t ws_size,
                              hipStream_t stream)
{
    const float* x  = (const float*)d_in[0];
    const float* Wf = (const float*)d_in[1];
    const float* Uf = (const float*)d_in[2];
    const float* bf = (const float*)d_in[3];
    const float* Wi = (const float*)d_in[4];
    const float* Ui = (const float*)d_in[5];
    const float* bi = (const float*)d_in[6];
    const float* Wo = (const float*)d_in[7];
    const float* Uo = (const float*)d_in[8];
    const float* bo = (const float*)d_in[9];
    const float* Wc = (const float*)d_in[10];
    const float* Uc = (const float*)d_in[11];
    const float* bc = (const float*)d_in[12];
    const float* Ahy = (const float*)d_in[13];
    const float* by  = (const float*)d_in[14];

    float* h_hist = (float*)d_ws;   // needs STEPS*NHID*4 = ~33.3 MB, poisoned 0xAA

    lstm_persistent<<<G, B, 0, stream>>>(x, Wf, Uf, bf, Wi, Ui, bi,
                                         Wo, Uo, bo, Wc, Uc, bc, h_hist);
    int muBlocks = (STEPS + 3) / 4;
    mu_kernel<<<muBlocks, 256, 0, stream>>>(h_hist, Ahy, by, (float*)d_out, STEPS);
}

// Round 3
// 26773.303 us; speedup vs baseline: 1.6779x; 1.2514x over previous
//
#include <hip/hip_runtime.h>

#define NHID 512
#define NXW  128
#define TLEN 16384
#define STEPS (TLEN - NXW)      // 16256
#define G    32                 // persistent workgroups (one CU each)
#define B    512                // threads per WG (8 waves)
#define RPW  16                 // hidden rows owned per WG

#define POISON_U 0xAAAAAAAAu    // harness re-poisons d_ws to 0xAA before every launch

#define FOR4(M)  M(0) M(1) M(2) M(3)
#define FOR16(M) M(0) M(1) M(2) M(3) M(4) M(5) M(6) M(7) \
                 M(8) M(9) M(10) M(11) M(12) M(13) M(14) M(15)

__device__ __forceinline__ float sigmoid_f(float v) { return 1.f / (1.f + __expf(-v)); }
__device__ __forceinline__ float tanh_f(float v)    { return 1.f - 2.f / (1.f + __expf(2.f * v)); }

// ---------------------------------------------------------------------------
// Persistent LSTM. WG g owns rows [g*16, g*16+16). 8 waves = 8 k-slices of 64.
// Lane l = output (gate q=l>>4, row g*16+(l&15)); wave w owns h[k] slice
// [w*64, w*64+64). Weights are PINNED in VGPRs via opaque asm defs (the R1/R2
// failure was the compiler rematerializing weight loads into the loop -> 256KB
// L2 traffic per CU per step ~= 4600cy). No __restrict__: h_hist stores may
// alias weights, which independently forbids load rematerialization.
// Flag-less sync: h published as h+2.0f in (1,3) -> bit pattern never equals
// 0xAA poison; each lane polls its own 4 bytes of h[t-1]. One barrier/step.
// ---------------------------------------------------------------------------
__launch_bounds__(B, 2)
__global__ void lstm_persistent(
    const float* x,
    const float* Wf, const float* Uf, const float* bf,
    const float* Wi, const float* Ui, const float* bi,
    const float* Wo, const float* Uo, const float* bo,
    const float* Wc, const float* Uc, const float* bc,
    float* h_hist)   // [STEPS][NHID] in ws (poisoned 0xAA)
{
    __shared__ float x_win[256];                    // x ring: refill every 128 steps
    __shared__ __align__(16) float h_buf[8][64];    // per-wave h-slice staging
    __shared__ float partials[2][B];                // double-buffered

    const int tid = threadIdx.x;
    const int g   = blockIdx.x;
    const int w   = tid >> 6;            // wave = k-slice 0..7
    const int l   = tid & 63;            // output 0..63
    const int q   = l >> 4;              // gate 0=f 1=i 2=o 3=c
    const int row = g * RPW + (l & 15);

    const float* Utab[4] = {Uf, Ui, Uo, Uc};
    const float* Wtab[4] = {Wf, Wi, Wo, Wc};
    const float* Btab[4] = {bf, bi, bo, bc};

    // load + PIN weights: 64 U floats + 16 W floats per thread
    const float4* Up = (const float4*)(Utab[q] + (size_t)row * NHID + w * 64);
    #define DECLU(i) float4 u##i = Up[i];
    FOR16(DECLU)
    const float4* Wp = (const float4*)(Wtab[q] + row * NXW + w * 16);
    #define DECLW(i) float4 wv##i = Wp[i];
    FOR4(DECLW)
    #define PIN(r) asm volatile("" : "+v"(r.x), "+v"(r.y), "+v"(r.z), "+v"(r.w));
    #define PINU(i) PIN(u##i)
    FOR16(PINU)
    #define PINW(i) PIN(wv##i)
    FOR4(PINW)

    float bias = 0.f, c_prev = 0.f;
    if (w == 0) bias = Btab[q][row];

    h_buf[w][l] = 0.f;                   // h[-1] = 0 (own wave reads only)

    for (int t = 0; t < STEPS; ++t) {
        // refill x window every 128 steps (covers x[t .. t+255])
        if ((t & 127) == 0) {
            __syncthreads();             // all waves done with prior window + partials
            if (tid < 256) {
                int gi = t + tid;
                x_win[tid] = (gi < TLEN) ? x[gi] : 0.f;
            }
            __syncthreads();
        }

        // x-projection partial (independent of h -> overlaps producer latency)
        float xacc = 0.f;
        {
            const int xb = (t & 127) + w * 16;
            #define XF(i) xacc += wv##i.x * x_win[xb + 4*i]     \
                                + wv##i.y * x_win[xb + 4*i + 1] \
                                + wv##i.z * x_win[xb + 4*i + 2] \
                                + wv##i.w * x_win[xb + 4*i + 3];
            FOR4(XF)
        }

        // poll own 4 bytes of h[t-1] (data != poison <=> published)
        if (t > 0) {
            const unsigned* src = (const unsigned*)
                (h_hist + (size_t)(t - 1) * NHID + w * 64 + l);
            unsigned vv; int guard = 0;
            do {
                vv = __hip_atomic_load(src, __ATOMIC_RELAXED, __HIP_MEMORY_SCOPE_AGENT);
            } while (vv == POISON_U && ++guard < (1 << 20));   // bounded: fail, don't hang
            h_buf[w][l] = __uint_as_float(vv) - 2.0f;
        }

        // U @ h slice: 64 FMA vs wave-uniform LDS broadcast reads
        float acc = xacc;
        const float4* hb4 = (const float4*)h_buf[w];
        #define UF(i) { float4 hv = hb4[i];                       \
                        acc += u##i.x * hv.x + u##i.y * hv.y      \
                             + u##i.z * hv.z + u##i.w * hv.w; }
        FOR16(UF)
        partials[t & 1][(w << 6) | l] = acc;
        __syncthreads();                 // the ONE per-step barrier

        // wave-0 tail: reduce 8 k-slices (own s=0 still in reg), activate,
        // combine via shuffle, publish
        if (w == 0) {
            const float* p = partials[t & 1];
            float pre = acc + bias;
            #pragma unroll
            for (int s2 = 1; s2 < 8; ++s2) pre += p[s2 * 64 + l];
            float a = (l < 48) ? sigmoid_f(pre) : tanh_f(pre);   // f,i,o / g
            float ai = __shfl(a, l + 16, 64);
            float ao = __shfl(a, l + 32, 64);
            float ag = __shfl(a, l + 48, 64);
            if (l < 16) {
                float c = a * c_prev + ai * ag;
                c_prev = c;
                float h = ao * tanh_f(c);
                __hip_atomic_store(h_hist + (size_t)t * NHID + g * RPW + l,
                                   h + 2.0f,
                                   __ATOMIC_RELAXED, __HIP_MEMORY_SCOPE_AGENT);
            }
        }
        // waves 1..7 sprint ahead to poll step t (partials double-buffered)
    }
}

// ---------------------------------------------------------------------------
// epilogue: mu[t] = Ahy . (h_hist[t] - 2) + by   (one wave per t)
// ---------------------------------------------------------------------------
__global__ void mu_kernel(const float* __restrict__ h_hist,
                          const float* __restrict__ Ahy,
                          const float* __restrict__ by,
                          float* __restrict__ outp, int steps)
{
    int wave = threadIdx.x >> 6;
    int lane = threadIdx.x & 63;
    int t = blockIdx.x * 4 + wave;
    if (t >= steps) return;
    const float* h = h_hist + (size_t)t * NHID;
    float p = 0.f;
    #pragma unroll
    for (int e = 0; e < 8; e++)
        p += Ahy[e * 64 + lane] * (h[e * 64 + lane] - 2.0f);
    #pragma unroll
    for (int off = 32; off; off >>= 1) p += __shfl_down(p, off, 64);
    if (lane == 0) outp[t] = p + by[0];
}

// ---------------------------------------------------------------------------
extern "C" void kernel_launch(void* const* d_in, const int* in_sizes, int n_in,
                              void* d_out, int out_size, void* d_ws, size_t ws_size,
                              hipStream_t stream)
{
    const float* x  = (const float*)d_in[0];
    const float* Wf = (const float*)d_in[1];
    const float* Uf = (const float*)d_in[2];
    const float* bf = (const float*)d_in[3];
    const float* Wi = (const float*)d_in[4];
    const float* Ui = (const float*)d_in[5];
    const float* bi = (const float*)d_in[6];
    const float* Wo = (const float*)d_in[7];
    const float* Uo = (const float*)d_in[8];
    const float* bo = (const float*)d_in[9];
    const float* Wc = (const float*)d_in[10];
    const float* Uc = (const float*)d_in[11];
    const float* bc = (const float*)d_in[12];
    const float* Ahy = (const float*)d_in[13];
    const float* by  = (const float*)d_in[14];

    float* h_hist = (float*)d_ws;   // STEPS*NHID*4 = ~33.3 MB, poisoned 0xAA

    lstm_persistent<<<G, B, 0, stream>>>(x, Wf, Uf, bf, Wi, Ui, bi,
                                         Wo, Uo, bo, Wc, Uc, bc, h_hist);
    int muBlocks = (STEPS + 3) / 4;
    mu_kernel<<<muBlocks, 256, 0, stream>>>(h_hist, Ahy, by, (float*)d_out, STEPS);
}